// Round 10
// baseline (394.441 us; speedup 1.0000x reference)
//
#include <hip/hip_runtime.h>

#define INV_SQRT2f 0.70710678118654752440f

// Analysis filters; synthesis filter f[k] = AF[9-k] (time reversal).
// Polyphase synthesis: out[2q+p] = sum_{j=0..4} AF[9-(2j+p)] * x[(q+2-j) mod Nin]
__constant__ float c_FAR[2][2][10] = {
  {{0.0f, -0.08838834764832f, 0.08838834764832f, 0.69587998903400f, 0.69587998903400f,
    0.08838834764832f, -0.08838834764832f, 0.01122679215254f, 0.01122679215254f, 0.0f},
   {0.0f, -0.01122679215254f, 0.01122679215254f, 0.08838834764832f, 0.08838834764832f,
    -0.69587998903400f, 0.69587998903400f, -0.08838834764832f, -0.08838834764832f, 0.0f}},
  {{0.01122679215254f, 0.01122679215254f, -0.08838834764832f, 0.08838834764832f, 0.69587998903400f,
    0.69587998903400f, 0.08838834764832f, -0.08838834764832f, 0.0f, 0.0f},
   {0.0f, 0.0f, -0.08838834764832f, -0.08838834764832f, 0.69587998903400f,
    -0.69587998903400f, 0.08838834764832f, 0.08838834764832f, 0.01122679215254f, -0.01122679215254f}}
};
__constant__ float c_DUAL[2][2][10] = {
  {{0.03516384f, 0.0f, -0.08832942f, 0.23389032f, 0.76027237f,
    0.58751830f, 0.0f, -0.11430184f, 0.0f, 0.0f},
   {0.0f, 0.0f, -0.11430184f, 0.0f, 0.58751830f,
    -0.76027237f, 0.23389032f, 0.08832942f, 0.0f, -0.03516384f}},
  {{0.0f, 0.0f, -0.11430184f, 0.0f, 0.58751830f,
    0.76027237f, 0.23389032f, -0.08832942f, 0.0f, 0.03516384f},
   {-0.03516384f, 0.0f, 0.08832942f, 0.23389032f, -0.76027237f,
    0.58751830f, 0.0f, -0.11430184f, 0.0f, 0.0f}}
};

// ---- staging: 12x12 spatial halo tile x 16 ch = 576 float4, 256 threads ----
template<int NSZ>
__device__ __forceinline__ void stage_copy(const float* __restrict__ src, float* __restrict__ dst,
                                           int ih0, int iw0, int tid) {
  #pragma unroll
  for (int it = 0; it < 3; ++it) {
    int e = tid + (it << 8);
    if (it < 2 || e < 576) {
      int r = e / 48;
      int cc = e - r * 48;
      int gr = (ih0 + r - 2) & (NSZ - 1);
      int gc = (iw0 + (cc >> 2) - 2) & (NSZ - 1);
      float4 v = *reinterpret_cast<const float4*>(src + (((size_t)gr * NSZ + gc) << 4) + ((cc & 3) << 2));
      *reinterpret_cast<float4*>(dst + (e << 2)) = v;
    }
  }
}

template<int NSZ>
__device__ __forceinline__ void stage_mix(const float* __restrict__ A, const float* __restrict__ B,
                                          float sgn, float* __restrict__ dst,
                                          int ih0, int iw0, int tid) {
  #pragma unroll
  for (int it = 0; it < 3; ++it) {
    int e = tid + (it << 8);
    if (it < 2 || e < 576) {
      int r = e / 48;
      int cc = e - r * 48;
      int gr = (ih0 + r - 2) & (NSZ - 1);
      int gc = (iw0 + (cc >> 2) - 2) & (NSZ - 1);
      size_t off = (((size_t)gr * NSZ + gc) << 4) + ((cc & 3) << 2);
      float4 a = *reinterpret_cast<const float4*>(A + off);
      float4 b = *reinterpret_cast<const float4*>(B + off);
      float4 v;
      v.x = (a.x + sgn * b.x) * INV_SQRT2f;
      v.y = (a.y + sgn * b.y) * INV_SQRT2f;
      v.z = (a.z + sgn * b.z) * INV_SQRT2f;
      v.w = (a.w + sgn * b.w) * INV_SQRT2f;
      *reinterpret_cast<float4*>(dst + (e << 2)) = v;
    }
  }
}

// ================= Stage A: q-shift (128 -> 256) — ping-pong half-tile pipeline =================
// bufA = {lo, LH} -> lo2; bufB = {HL, HH} -> h2. stageB's HBM loads overlap col-A compute.
__global__ __launch_bounds__(256) void qshift_kernel(
    const float* __restrict__ w2, const float* __restrict__ loT, float* __restrict__ mid)
{
  __shared__ __align__(16) float sA[2][12][12][16];
  __shared__ __align__(16) float sB[2][12][12][16];

  const int tid = threadIdx.x;
  const int c = tid & 15;
  const int s = tid >> 4;
  const int tw = blockIdx.x;
  const int th = blockIdx.y;
  const int b  = blockIdx.z & 3;
  const int q  = blockIdx.z >> 2;
  const int m = q >> 1, n = q & 1;
  const int j1 = m ^ n;
  const float sgn = m ? -1.0f : 1.0f;
  const int ih0 = th * 8, iw0 = tw * 8;
  const size_t plane = (size_t)128 * 128 * 16;

  const float* pA1 = w2 + ((size_t)((0 * 2 + j1) * 3 + 1) * 4 + b) * plane;
  const float* pA2 = w2 + ((size_t)((0 * 2 + j1) * 3 + 2) * 4 + b) * plane;
  const float* pB1 = w2 + ((size_t)((1 * 2 + (1 ^ j1)) * 3 + 1) * 4 + b) * plane;
  const float* pB2 = w2 + ((size_t)((1 * 2 + (1 ^ j1)) * 3 + 2) * 4 + b) * plane;

  stage_copy<128>(loT + ((size_t)(m * 2 + n) * 4 + b) * plane, &sA[0][0][0][0], ih0, iw0, tid);
  stage_mix<128>(w2 + ((size_t)((0 * 2 + j1) * 3 + 0) * 4 + b) * plane,
                 w2 + ((size_t)((1 * 2 + (1 ^ j1)) * 3 + 0) * 4 + b) * plane,
                 sgn, &sA[1][0][0][0], ih0, iw0, tid);
  __syncthreads();

  const int pw = s & 1, qw = s >> 1;
  float flp[5], fhp[5];
  #pragma unroll
  for (int j = 0; j < 5; ++j) {
    flp[j] = c_DUAL[n][0][9 - (2 * j + pw)];
    fhp[j] = c_DUAL[n][1][9 - (2 * j + pw)];
  }

  // col pass A -> lo2 (stage B issued alongside; compiler overlaps loads with ds_reads)
  float lo2[12];
  #pragma unroll
  for (int r = 0; r < 12; ++r) {
    float lo_v = 0.f;
    #pragma unroll
    for (int j = 0; j < 5; ++j) {
      int x = qw + 4 - j;
      lo_v += flp[j] * sA[0][r][x][c] + fhp[j] * sA[1][r][x][c];
    }
    lo2[r] = lo_v;
  }
  stage_mix<128>(pA1, pB1, sgn, &sB[0][0][0][0], ih0, iw0, tid);
  stage_mix<128>(pA2, pB2, sgn, &sB[1][0][0][0], ih0, iw0, tid);

  // row-pass lo-part
  float acc[16];
  #pragma unroll
  for (int nh = 0; nh < 16; ++nh) {
    int ph = nh & 1, qh = nh >> 1;
    float v = 0.f;
    #pragma unroll
    for (int j = 0; j < 5; ++j)
      v += c_DUAL[m][0][9 - (2 * j + ph)] * lo2[qh + 4 - j];
    acc[nh] = v;
  }
  __syncthreads();

  // col pass B -> h2; row-pass h-part
  float h2[12];
  #pragma unroll
  for (int r = 0; r < 12; ++r) {
    float h_v = 0.f;
    #pragma unroll
    for (int j = 0; j < 5; ++j) {
      int x = qw + 4 - j;
      h_v += flp[j] * sB[0][r][x][c] + fhp[j] * sB[1][r][x][c];
    }
    h2[r] = h_v;
  }
  float* outQ = mid + ((size_t)q * 4 + b) * (size_t)(256 * 256 * 16);
  #pragma unroll
  for (int nh = 0; nh < 16; ++nh) {
    int ph = nh & 1, qh = nh >> 1;
    float v = acc[nh];
    #pragma unroll
    for (int j = 0; j < 5; ++j)
      v += c_DUAL[m][1][9 - (2 * j + ph)] * h2[qh + 4 - j];
    outQ[(((size_t)(ih0 * 2 + nh)) * 256 + (size_t)(iw0 * 2 + s)) * 16 + c] = v;
  }
}

// ================= Stage B: Farras (256 -> 512) — ping-pong half-tile pipeline =================
// Per quadrant: stageA{lo,LH}->bufA; bar; colA->lo2 (+issue stageB{HL,HH}->bufB);
// row-acc lo; bar; colB->h2; row-acc h; next quadrant's stageA overlaps colB.
// Only 2 barriers/quadrant; both staging phases hide under compute. Runtime q-loop.
__global__ __launch_bounds__(256) void farras_kernel(
    const float* __restrict__ w1, const float* __restrict__ mid, float* __restrict__ out)
{
  __shared__ __align__(16) float sA[2][12][12][16];
  __shared__ __align__(16) float sB[2][12][12][16];

  const int tid = threadIdx.x;
  const int c = tid & 15;
  const int s = tid >> 4;
  const int tw = blockIdx.x;
  const int th = blockIdx.y;
  const int b  = blockIdx.z;
  const int ih0 = th * 8, iw0 = tw * 8;
  const size_t plane = (size_t)256 * 256 * 16;
  const int pw = s & 1, qw = s >> 1;

  float acc[16];
  #pragma unroll
  for (int i = 0; i < 16; ++i) acc[i] = 0.f;

  // prologue: stage quadrant 0's {lo, LH}
  {
    const float* pA0 = w1 + ((size_t)((0 * 2 + 0) * 3 + 0) * 4 + b) * plane;
    const float* pB0 = w1 + ((size_t)((1 * 2 + 1) * 3 + 0) * 4 + b) * plane;
    stage_copy<256>(mid + ((size_t)0 * 4 + b) * plane, &sA[0][0][0][0], ih0, iw0, tid);
    stage_mix<256>(pA0, pB0, 1.0f, &sA[1][0][0][0], ih0, iw0, tid);
  }

  #pragma unroll 1
  for (int q = 0; q < 4; ++q) {
    const int m = q >> 1, n = q & 1;
    const int j1 = m ^ n;
    const float sgn = m ? -1.0f : 1.0f;

    const float* pA1 = w1 + ((size_t)((0 * 2 + j1) * 3 + 1) * 4 + b) * plane;
    const float* pA2 = w1 + ((size_t)((0 * 2 + j1) * 3 + 2) * 4 + b) * plane;
    const float* pB1 = w1 + ((size_t)((1 * 2 + (1 ^ j1)) * 3 + 1) * 4 + b) * plane;
    const float* pB2 = w1 + ((size_t)((1 * 2 + (1 ^ j1)) * 3 + 2) * 4 + b) * plane;

    float flp[5], fhp[5];
    #pragma unroll
    for (int j = 0; j < 5; ++j) {
      flp[j] = c_FAR[n][0][9 - (2 * j + pw)];
      fhp[j] = c_FAR[n][1][9 - (2 * j + pw)];
    }

    __syncthreads();   // sA(q) writes visible; also protects sB(q-1) reads vs sB(q) writes

    // col pass A -> lo2; stage B issued alongside (HBM latency hides under ds_read+FMA)
    float lo2[12];
    #pragma unroll
    for (int r = 0; r < 12; ++r) {
      float lo_v = 0.f;
      #pragma unroll
      for (int j = 0; j < 5; ++j) {
        int x = qw + 4 - j;
        lo_v += flp[j] * sA[0][r][x][c] + fhp[j] * sA[1][r][x][c];
      }
      lo2[r] = lo_v;
    }
    stage_mix<256>(pA1, pB1, sgn, &sB[0][0][0][0], ih0, iw0, tid);
    stage_mix<256>(pA2, pB2, sgn, &sB[1][0][0][0], ih0, iw0, tid);

    // row-pass lo-part
    #pragma unroll
    for (int nh = 0; nh < 16; ++nh) {
      int ph = nh & 1, qh = nh >> 1;
      float v = 0.f;
      #pragma unroll
      for (int j = 0; j < 5; ++j)
        v += c_FAR[m][0][9 - (2 * j + ph)] * lo2[qh + 4 - j];
      acc[nh] += v;
    }

    __syncthreads();   // sB(q) writes visible; also protects sA(q) reads vs sA(q+1) writes

    // col pass B -> h2; next quadrant's stage A issued alongside
    float h2[12];
    #pragma unroll
    for (int r = 0; r < 12; ++r) {
      float h_v = 0.f;
      #pragma unroll
      for (int j = 0; j < 5; ++j) {
        int x = qw + 4 - j;
        h_v += flp[j] * sB[0][r][x][c] + fhp[j] * sB[1][r][x][c];
      }
      h2[r] = h_v;
    }
    if (q < 3) {
      const int q2 = q + 1;
      const int j2 = (q2 >> 1) ^ (q2 & 1);
      const float* nA0 = w1 + ((size_t)((0 * 2 + j2) * 3 + 0) * 4 + b) * plane;
      const float* nB0 = w1 + ((size_t)((1 * 2 + (1 ^ j2)) * 3 + 0) * 4 + b) * plane;
      stage_copy<256>(mid + ((size_t)q2 * 4 + b) * plane, &sA[0][0][0][0], ih0, iw0, tid);
      stage_mix<256>(nA0, nB0, (q2 >> 1) ? -1.0f : 1.0f, &sA[1][0][0][0], ih0, iw0, tid);
    }

    // row-pass h-part
    #pragma unroll
    for (int nh = 0; nh < 16; ++nh) {
      int ph = nh & 1, qh = nh >> 1;
      float v = 0.f;
      #pragma unroll
      for (int j = 0; j < 5; ++j)
        v += c_FAR[m][1][9 - (2 * j + ph)] * h2[qh + 4 - j];
      acc[nh] += v;
    }
  }

  #pragma unroll
  for (int nh = 0; nh < 16; ++nh) {
    size_t gh = (size_t)(ih0 * 2 + nh);
    size_t gw = (size_t)(iw0 * 2 + s);
    out[(((size_t)b * 512 + gh) * 512 + gw) * 16 + c] = acc[nh] * 0.5f;
  }
}

extern "C" void kernel_launch(void* const* d_in, const int* in_sizes, int n_in,
                              void* d_out, int out_size, void* d_ws, size_t ws_size,
                              hipStream_t stream) {
  const float* w1 = (const float*)d_in[0];   // [2,2,3,4,256,256,16]
  const float* w2 = (const float*)d_in[1];   // [2,2,3,4,128,128,16]
  const float* lo = (const float*)d_in[2];   // [2,2,4,128,128,16]
  float* out = (float*)d_out;                // [4,512,512,16]
  float* mid = (float*)d_ws;                 // [4 quadrants][4][256][256][16] = 64 MiB

  qshift_kernel<<<dim3(16, 16, 16), 256, 0, stream>>>(w2, lo, mid);
  farras_kernel<<<dim3(32, 32, 4), 256, 0, stream>>>(w1, mid, out);
}

// Round 11
// 251.978 us; speedup vs baseline: 1.5654x; 1.5654x over previous
//
#include <hip/hip_runtime.h>

#define INV_SQRT2f 0.70710678118654752440f

// Analysis filters; synthesis filter f[k] = AF[9-k] (time reversal).
// Polyphase synthesis: out[2q+p] = sum_{j=0..4} AF[9-(2j+p)] * x[(q+2-j) mod Nin]
// Scatter form (verified R3): col-row r contributes acc[2t+p] += AF[2(r-t)+1-p]*v, t in [r-4,r]&[0,7]
__constant__ float c_FAR[2][2][10] = {
  {{0.0f, -0.08838834764832f, 0.08838834764832f, 0.69587998903400f, 0.69587998903400f,
    0.08838834764832f, -0.08838834764832f, 0.01122679215254f, 0.01122679215254f, 0.0f},
   {0.0f, -0.01122679215254f, 0.01122679215254f, 0.08838834764832f, 0.08838834764832f,
    -0.69587998903400f, 0.69587998903400f, -0.08838834764832f, -0.08838834764832f, 0.0f}},
  {{0.01122679215254f, 0.01122679215254f, -0.08838834764832f, 0.08838834764832f, 0.69587998903400f,
    0.69587998903400f, 0.08838834764832f, -0.08838834764832f, 0.0f, 0.0f},
   {0.0f, 0.0f, -0.08838834764832f, -0.08838834764832f, 0.69587998903400f,
    -0.69587998903400f, 0.08838834764832f, 0.08838834764832f, 0.01122679215254f, -0.01122679215254f}}
};
__constant__ float c_DUAL[2][2][10] = {
  {{0.03516384f, 0.0f, -0.08832942f, 0.23389032f, 0.76027237f,
    0.58751830f, 0.0f, -0.11430184f, 0.0f, 0.0f},
   {0.0f, 0.0f, -0.11430184f, 0.0f, 0.58751830f,
    -0.76027237f, 0.23389032f, 0.08832942f, 0.0f, -0.03516384f}},
  {{0.0f, 0.0f, -0.11430184f, 0.0f, 0.58751830f,
    0.76027237f, 0.23389032f, -0.08832942f, 0.0f, 0.03516384f},
   {-0.03516384f, 0.0f, 0.08832942f, 0.23389032f, -0.76027237f,
    0.58751830f, 0.0f, -0.11430184f, 0.0f, 0.0f}}
};

// ---- staging: 12x12 spatial halo tile x 16 ch = 576 float4, 256 threads ----
template<int NSZ>
__device__ __forceinline__ void stage_copy(const float* __restrict__ src, float* __restrict__ dst,
                                           int ih0, int iw0, int tid) {
  #pragma unroll
  for (int it = 0; it < 3; ++it) {
    int e = tid + (it << 8);
    if (it < 2 || e < 576) {
      int r = e / 48;
      int cc = e - r * 48;
      int gr = (ih0 + r - 2) & (NSZ - 1);
      int gc = (iw0 + (cc >> 2) - 2) & (NSZ - 1);
      float4 v = *reinterpret_cast<const float4*>(src + (((size_t)gr * NSZ + gc) << 4) + ((cc & 3) << 2));
      *reinterpret_cast<float4*>(dst + (e << 2)) = v;
    }
  }
}

template<int NSZ>
__device__ __forceinline__ void stage_mix(const float* __restrict__ A, const float* __restrict__ B,
                                          float sgn, float* __restrict__ dst,
                                          int ih0, int iw0, int tid) {
  #pragma unroll
  for (int it = 0; it < 3; ++it) {
    int e = tid + (it << 8);
    if (it < 2 || e < 576) {
      int r = e / 48;
      int cc = e - r * 48;
      int gr = (ih0 + r - 2) & (NSZ - 1);
      int gc = (iw0 + (cc >> 2) - 2) & (NSZ - 1);
      size_t off = (((size_t)gr * NSZ + gc) << 4) + ((cc & 3) << 2);
      float4 a = *reinterpret_cast<const float4*>(A + off);
      float4 b = *reinterpret_cast<const float4*>(B + off);
      float4 v;
      v.x = (a.x + sgn * b.x) * INV_SQRT2f;
      v.y = (a.y + sgn * b.y) * INV_SQRT2f;
      v.z = (a.z + sgn * b.z) * INV_SQRT2f;
      v.w = (a.w + sgn * b.w) * INV_SQRT2f;
      *reinterpret_cast<float4*>(dst + (e << 2)) = v;
    }
  }
}

// ---- one phase: col pass over 2 LDS planes -> scatter-accumulate into acc ----
// rt[10] = row taps AF[m][lh][0..9] (runtime-loaded). All array indices static after unroll.
__device__ __forceinline__ void col_scatter(const float (*sP0)[12][16], const float (*sP1)[12][16],
                                            const float* flp, const float* fhp,
                                            const float* rt, int qw, int c, float (&acc)[16]) {
  #pragma unroll
  for (int r = 0; r < 12; ++r) {
    float v = 0.f;
    #pragma unroll
    for (int j = 0; j < 5; ++j) {
      int x = qw + 4 - j;
      v += flp[j] * sP0[r][x][c] + fhp[j] * sP1[r][x][c];
    }
    #pragma unroll
    for (int d = 0; d < 5; ++d) {
      int t = r - d;
      if (t >= 0 && t <= 7) {
        acc[2 * t]     += rt[2 * d + 1] * v;
        acc[2 * t + 1] += rt[2 * d]     * v;
      }
    }
  }
}

// ================= Stage A: q-shift (128 -> 256) — two-phase, 18.4 KB LDS =================
__global__ __launch_bounds__(256) void qshift_kernel(
    const float* __restrict__ w2, const float* __restrict__ loT, float* __restrict__ mid)
{
  __shared__ __align__(16) float sP[2][12][12][16];   // 18432 B -> 8 blocks/CU

  const int tid = threadIdx.x;
  const int c = tid & 15;
  const int s = tid >> 4;
  const int tw = blockIdx.x;
  const int th = blockIdx.y;
  const int b  = blockIdx.z & 3;
  const int q  = blockIdx.z >> 2;
  const int m = q >> 1, n = q & 1;
  const int j1 = m ^ n;
  const float sgn = m ? -1.0f : 1.0f;
  const int ih0 = th * 8, iw0 = tw * 8;
  const size_t plane = (size_t)128 * 128 * 16;
  const int pw = s & 1, qw = s >> 1;

  float flp[5], fhp[5];
  #pragma unroll
  for (int j = 0; j < 5; ++j) {
    flp[j] = c_DUAL[n][0][9 - (2 * j + pw)];
    fhp[j] = c_DUAL[n][1][9 - (2 * j + pw)];
  }
  float acc[16];
  #pragma unroll
  for (int i = 0; i < 16; ++i) acc[i] = 0.f;

  // phase A: {lo, LH}
  stage_copy<128>(loT + ((size_t)(m * 2 + n) * 4 + b) * plane, &sP[0][0][0][0], ih0, iw0, tid);
  stage_mix<128>(w2 + ((size_t)((0 * 2 + j1) * 3 + 0) * 4 + b) * plane,
                 w2 + ((size_t)((1 * 2 + (1 ^ j1)) * 3 + 0) * 4 + b) * plane,
                 sgn, &sP[1][0][0][0], ih0, iw0, tid);
  __syncthreads();
  {
    float rt[10];
    #pragma unroll
    for (int k = 0; k < 10; ++k) rt[k] = c_DUAL[m][0][k];
    col_scatter(sP[0], sP[1], flp, fhp, rt, qw, c, acc);
  }
  __syncthreads();

  // phase B: {HL, HH}
  stage_mix<128>(w2 + ((size_t)((0 * 2 + j1) * 3 + 1) * 4 + b) * plane,
                 w2 + ((size_t)((1 * 2 + (1 ^ j1)) * 3 + 1) * 4 + b) * plane,
                 sgn, &sP[0][0][0][0], ih0, iw0, tid);
  stage_mix<128>(w2 + ((size_t)((0 * 2 + j1) * 3 + 2) * 4 + b) * plane,
                 w2 + ((size_t)((1 * 2 + (1 ^ j1)) * 3 + 2) * 4 + b) * plane,
                 sgn, &sP[1][0][0][0], ih0, iw0, tid);
  __syncthreads();
  {
    float rt[10];
    #pragma unroll
    for (int k = 0; k < 10; ++k) rt[k] = c_DUAL[m][1][k];
    col_scatter(sP[0], sP[1], flp, fhp, rt, qw, c, acc);
  }

  float* outQ = mid + ((size_t)q * 4 + b) * (size_t)(256 * 256 * 16);
  #pragma unroll
  for (int nh = 0; nh < 16; ++nh) {
    outQ[(((size_t)(ih0 * 2 + nh)) * 256 + (size_t)(iw0 * 2 + s)) * 16 + c] = acc[nh];
  }
}

// ================= Stage B: Farras (256 -> 512) — two-phase, 18.4 KB LDS =================
__global__ __launch_bounds__(256) void farras_kernel(
    const float* __restrict__ w1, const float* __restrict__ mid, float* __restrict__ out)
{
  __shared__ __align__(16) float sP[2][12][12][16];   // 18432 B -> 8 blocks/CU

  const int tid = threadIdx.x;
  const int c = tid & 15;
  const int s = tid >> 4;
  const int tw = blockIdx.x;
  const int th = blockIdx.y;
  const int b  = blockIdx.z;
  const int ih0 = th * 8, iw0 = tw * 8;
  const size_t plane = (size_t)256 * 256 * 16;
  const int pw = s & 1, qw = s >> 1;

  float acc[16];
  #pragma unroll
  for (int i = 0; i < 16; ++i) acc[i] = 0.f;

  #pragma unroll 1
  for (int q = 0; q < 4; ++q) {
    const int m = q >> 1, n = q & 1;
    const int j1 = m ^ n;
    const float sgn = m ? -1.0f : 1.0f;

    float flp[5], fhp[5];
    #pragma unroll
    for (int j = 0; j < 5; ++j) {
      flp[j] = c_FAR[n][0][9 - (2 * j + pw)];
      fhp[j] = c_FAR[n][1][9 - (2 * j + pw)];
    }

    // phase A: {lo(mid), LH}
    __syncthreads();   // previous phase-B reads complete before overwrite
    stage_copy<256>(mid + ((size_t)q * 4 + b) * plane, &sP[0][0][0][0], ih0, iw0, tid);
    stage_mix<256>(w1 + ((size_t)((0 * 2 + j1) * 3 + 0) * 4 + b) * plane,
                   w1 + ((size_t)((1 * 2 + (1 ^ j1)) * 3 + 0) * 4 + b) * plane,
                   sgn, &sP[1][0][0][0], ih0, iw0, tid);
    __syncthreads();
    {
      float rt[10];
      #pragma unroll
      for (int k = 0; k < 10; ++k) rt[k] = c_FAR[m][0][k];
      col_scatter(sP[0], sP[1], flp, fhp, rt, qw, c, acc);
    }

    // phase B: {HL, HH}
    __syncthreads();   // phase-A reads complete before overwrite
    stage_mix<256>(w1 + ((size_t)((0 * 2 + j1) * 3 + 1) * 4 + b) * plane,
                   w1 + ((size_t)((1 * 2 + (1 ^ j1)) * 3 + 1) * 4 + b) * plane,
                   sgn, &sP[0][0][0][0], ih0, iw0, tid);
    stage_mix<256>(w1 + ((size_t)((0 * 2 + j1) * 3 + 2) * 4 + b) * plane,
                   w1 + ((size_t)((1 * 2 + (1 ^ j1)) * 3 + 2) * 4 + b) * plane,
                   sgn, &sP[1][0][0][0], ih0, iw0, tid);
    __syncthreads();
    {
      float rt[10];
      #pragma unroll
      for (int k = 0; k < 10; ++k) rt[k] = c_FAR[m][1][k];
      col_scatter(sP[0], sP[1], flp, fhp, rt, qw, c, acc);
    }
  }

  #pragma unroll
  for (int nh = 0; nh < 16; ++nh) {
    size_t gh = (size_t)(ih0 * 2 + nh);
    size_t gw = (size_t)(iw0 * 2 + s);
    out[(((size_t)b * 512 + gh) * 512 + gw) * 16 + c] = acc[nh] * 0.5f;
  }
}

extern "C" void kernel_launch(void* const* d_in, const int* in_sizes, int n_in,
                              void* d_out, int out_size, void* d_ws, size_t ws_size,
                              hipStream_t stream) {
  const float* w1 = (const float*)d_in[0];   // [2,2,3,4,256,256,16]
  const float* w2 = (const float*)d_in[1];   // [2,2,3,4,128,128,16]
  const float* lo = (const float*)d_in[2];   // [2,2,4,128,128,16]
  float* out = (float*)d_out;                // [4,512,512,16]
  float* mid = (float*)d_ws;                 // [4 quadrants][4][256][256][16] = 64 MiB

  qshift_kernel<<<dim3(16, 16, 16), 256, 0, stream>>>(w2, lo, mid);
  farras_kernel<<<dim3(32, 32, 4), 256, 0, stream>>>(w1, mid, out);
}

// Round 12
// 250.983 us; speedup vs baseline: 1.5716x; 1.0040x over previous
//
#include <hip/hip_runtime.h>

#define INV_SQRT2f 0.70710678118654752440f

// Analysis filters; synthesis filter f[k] = AF[9-k] (time reversal).
// Polyphase synthesis: out[2q+p] = sum_{j=0..4} AF[9-(2j+p)] * x[(q+2-j) mod Nin]
// Scatter form (verified R3/R11): col-row r adds acc[2t+p] += AF[2(r-t)+1-p]*v, t in [r-4,r]&[0,7]
__constant__ float c_FAR[2][2][10] = {
  {{0.0f, -0.08838834764832f, 0.08838834764832f, 0.69587998903400f, 0.69587998903400f,
    0.08838834764832f, -0.08838834764832f, 0.01122679215254f, 0.01122679215254f, 0.0f},
   {0.0f, -0.01122679215254f, 0.01122679215254f, 0.08838834764832f, 0.08838834764832f,
    -0.69587998903400f, 0.69587998903400f, -0.08838834764832f, -0.08838834764832f, 0.0f}},
  {{0.01122679215254f, 0.01122679215254f, -0.08838834764832f, 0.08838834764832f, 0.69587998903400f,
    0.69587998903400f, 0.08838834764832f, -0.08838834764832f, 0.0f, 0.0f},
   {0.0f, 0.0f, -0.08838834764832f, -0.08838834764832f, 0.69587998903400f,
    -0.69587998903400f, 0.08838834764832f, 0.08838834764832f, 0.01122679215254f, -0.01122679215254f}}
};
__constant__ float c_DUAL[2][2][10] = {
  {{0.03516384f, 0.0f, -0.08832942f, 0.23389032f, 0.76027237f,
    0.58751830f, 0.0f, -0.11430184f, 0.0f, 0.0f},
   {0.0f, 0.0f, -0.11430184f, 0.0f, 0.58751830f,
    -0.76027237f, 0.23389032f, 0.08832942f, 0.0f, -0.03516384f}},
  {{0.0f, 0.0f, -0.11430184f, 0.0f, 0.58751830f,
    0.76027237f, 0.23389032f, -0.08832942f, 0.0f, 0.03516384f},
   {-0.03516384f, 0.0f, 0.08832942f, 0.23389032f, -0.76027237f,
    0.58751830f, 0.0f, -0.11430184f, 0.0f, 0.0f}}
};

// ---- staging: 12x12 spatial halo tile x 16 ch = 576 float4, 256 threads ----
template<int NSZ>
__device__ __forceinline__ void stage_copy(const float* __restrict__ src, float* __restrict__ dst,
                                           int ih0, int iw0, int tid) {
  #pragma unroll
  for (int it = 0; it < 3; ++it) {
    int e = tid + (it << 8);
    if (it < 2 || e < 576) {
      int r = e / 48;
      int cc = e - r * 48;
      int gr = (ih0 + r - 2) & (NSZ - 1);
      int gc = (iw0 + (cc >> 2) - 2) & (NSZ - 1);
      float4 v = *reinterpret_cast<const float4*>(src + (((size_t)gr * NSZ + gc) << 4) + ((cc & 3) << 2));
      *reinterpret_cast<float4*>(dst + (e << 2)) = v;
    }
  }
}

template<int NSZ>
__device__ __forceinline__ void stage_mix(const float* __restrict__ A, const float* __restrict__ B,
                                          float sgn, float* __restrict__ dst,
                                          int ih0, int iw0, int tid) {
  #pragma unroll
  for (int it = 0; it < 3; ++it) {
    int e = tid + (it << 8);
    if (it < 2 || e < 576) {
      int r = e / 48;
      int cc = e - r * 48;
      int gr = (ih0 + r - 2) & (NSZ - 1);
      int gc = (iw0 + (cc >> 2) - 2) & (NSZ - 1);
      size_t off = (((size_t)gr * NSZ + gc) << 4) + ((cc & 3) << 2);
      float4 a = *reinterpret_cast<const float4*>(A + off);
      float4 b = *reinterpret_cast<const float4*>(B + off);
      float4 v;
      v.x = (a.x + sgn * b.x) * INV_SQRT2f;
      v.y = (a.y + sgn * b.y) * INV_SQRT2f;
      v.z = (a.z + sgn * b.z) * INV_SQRT2f;
      v.w = (a.w + sgn * b.w) * INV_SQRT2f;
      *reinterpret_cast<float4*>(dst + (e << 2)) = v;
    }
  }
}

// ---- one phase: col pass over 2 LDS planes -> scatter-accumulate into acc ----
// rowtap = &c_XXX[m][lh][0]: wave-uniform constant-memory base; every rowtap[k]
// (k static after unroll) is an s_load -> SGPR, zero VGPR cost.
__device__ __forceinline__ void col_scatter(const float (*sP0)[12][16], const float (*sP1)[12][16],
                                            const float* flp, const float* fhp,
                                            const float* __restrict__ rowtap,
                                            int qw, int c, float (&acc)[16]) {
  #pragma unroll
  for (int r = 0; r < 12; ++r) {
    float v = 0.f;
    #pragma unroll
    for (int j = 0; j < 5; ++j) {
      int x = qw + 4 - j;
      v += flp[j] * sP0[r][x][c] + fhp[j] * sP1[r][x][c];
    }
    #pragma unroll
    for (int d = 0; d < 5; ++d) {
      int t = r - d;
      if (t >= 0 && t <= 7) {
        acc[2 * t]     += rowtap[2 * d + 1] * v;
        acc[2 * t + 1] += rowtap[2 * d]     * v;
      }
    }
  }
}

// ================= Stage A: q-shift (128 -> 256) — two-phase, 18.4 KB LDS =================
__global__ __launch_bounds__(256) void qshift_kernel(
    const float* __restrict__ w2, const float* __restrict__ loT, float* __restrict__ mid)
{
  __shared__ __align__(16) float sP[2][12][12][16];   // 18432 B

  const int tid = threadIdx.x;
  const int c = tid & 15;
  const int s = tid >> 4;
  const int tw = blockIdx.x;
  const int th = blockIdx.y;
  const int b  = blockIdx.z & 3;
  const int q  = blockIdx.z >> 2;
  const int m = q >> 1, n = q & 1;
  const int j1 = m ^ n;
  const float sgn = m ? -1.0f : 1.0f;
  const int ih0 = th * 8, iw0 = tw * 8;
  const size_t plane = (size_t)128 * 128 * 16;
  const int pw = s & 1, qw = s >> 1;

  float flp[5], fhp[5];
  #pragma unroll
  for (int j = 0; j < 5; ++j) {
    flp[j] = c_DUAL[n][0][9 - (2 * j + pw)];
    fhp[j] = c_DUAL[n][1][9 - (2 * j + pw)];
  }
  float acc[16];
  #pragma unroll
  for (int i = 0; i < 16; ++i) acc[i] = 0.f;

  // phase A: {lo, LH}
  stage_copy<128>(loT + ((size_t)(m * 2 + n) * 4 + b) * plane, &sP[0][0][0][0], ih0, iw0, tid);
  stage_mix<128>(w2 + ((size_t)((0 * 2 + j1) * 3 + 0) * 4 + b) * plane,
                 w2 + ((size_t)((1 * 2 + (1 ^ j1)) * 3 + 0) * 4 + b) * plane,
                 sgn, &sP[1][0][0][0], ih0, iw0, tid);
  __syncthreads();
  col_scatter(sP[0], sP[1], flp, fhp, &c_DUAL[m][0][0], qw, c, acc);
  __syncthreads();

  // phase B: {HL, HH}
  stage_mix<128>(w2 + ((size_t)((0 * 2 + j1) * 3 + 1) * 4 + b) * plane,
                 w2 + ((size_t)((1 * 2 + (1 ^ j1)) * 3 + 1) * 4 + b) * plane,
                 sgn, &sP[0][0][0][0], ih0, iw0, tid);
  stage_mix<128>(w2 + ((size_t)((0 * 2 + j1) * 3 + 2) * 4 + b) * plane,
                 w2 + ((size_t)((1 * 2 + (1 ^ j1)) * 3 + 2) * 4 + b) * plane,
                 sgn, &sP[1][0][0][0], ih0, iw0, tid);
  __syncthreads();
  col_scatter(sP[0], sP[1], flp, fhp, &c_DUAL[m][1][0], qw, c, acc);

  float* outQ = mid + ((size_t)q * 4 + b) * (size_t)(256 * 256 * 16);
  #pragma unroll
  for (int nh = 0; nh < 16; ++nh) {
    outQ[(((size_t)(ih0 * 2 + nh)) * 256 + (size_t)(iw0 * 2 + s)) * 16 + c] = acc[nh];
  }
}

// ================= Stage B: Farras (256 -> 512) — two-phase, 18.4 KB LDS =================
__global__ __launch_bounds__(256) void farras_kernel(
    const float* __restrict__ w1, const float* __restrict__ mid, float* __restrict__ out)
{
  __shared__ __align__(16) float sP[2][12][12][16];   // 18432 B

  const int tid = threadIdx.x;
  const int c = tid & 15;
  const int s = tid >> 4;
  const int tw = blockIdx.x;
  const int th = blockIdx.y;
  const int b  = blockIdx.z;
  const int ih0 = th * 8, iw0 = tw * 8;
  const size_t plane = (size_t)256 * 256 * 16;
  const int pw = s & 1, qw = s >> 1;

  float acc[16];
  #pragma unroll
  for (int i = 0; i < 16; ++i) acc[i] = 0.f;

  #pragma unroll 1
  for (int q = 0; q < 4; ++q) {
    const int m = q >> 1, n = q & 1;
    const int j1 = m ^ n;
    const float sgn = m ? -1.0f : 1.0f;

    float flp[5], fhp[5];
    #pragma unroll
    for (int j = 0; j < 5; ++j) {
      flp[j] = c_FAR[n][0][9 - (2 * j + pw)];
      fhp[j] = c_FAR[n][1][9 - (2 * j + pw)];
    }

    // phase A: {lo(mid), LH}
    __syncthreads();   // previous phase-B reads complete before overwrite
    stage_copy<256>(mid + ((size_t)q * 4 + b) * plane, &sP[0][0][0][0], ih0, iw0, tid);
    stage_mix<256>(w1 + ((size_t)((0 * 2 + j1) * 3 + 0) * 4 + b) * plane,
                   w1 + ((size_t)((1 * 2 + (1 ^ j1)) * 3 + 0) * 4 + b) * plane,
                   sgn, &sP[1][0][0][0], ih0, iw0, tid);
    __syncthreads();
    col_scatter(sP[0], sP[1], flp, fhp, &c_FAR[m][0][0], qw, c, acc);

    // phase B: {HL, HH}
    __syncthreads();   // phase-A reads complete before overwrite
    stage_mix<256>(w1 + ((size_t)((0 * 2 + j1) * 3 + 1) * 4 + b) * plane,
                   w1 + ((size_t)((1 * 2 + (1 ^ j1)) * 3 + 1) * 4 + b) * plane,
                   sgn, &sP[0][0][0][0], ih0, iw0, tid);
    stage_mix<256>(w1 + ((size_t)((0 * 2 + j1) * 3 + 2) * 4 + b) * plane,
                   w1 + ((size_t)((1 * 2 + (1 ^ j1)) * 3 + 2) * 4 + b) * plane,
                   sgn, &sP[1][0][0][0], ih0, iw0, tid);
    __syncthreads();
    col_scatter(sP[0], sP[1], flp, fhp, &c_FAR[m][1][0], qw, c, acc);
  }

  #pragma unroll
  for (int nh = 0; nh < 16; ++nh) {
    size_t gh = (size_t)(ih0 * 2 + nh);
    size_t gw = (size_t)(iw0 * 2 + s);
    out[(((size_t)b * 512 + gh) * 512 + gw) * 16 + c] = acc[nh] * 0.5f;
  }
}

extern "C" void kernel_launch(void* const* d_in, const int* in_sizes, int n_in,
                              void* d_out, int out_size, void* d_ws, size_t ws_size,
                              hipStream_t stream) {
  const float* w1 = (const float*)d_in[0];   // [2,2,3,4,256,256,16]
  const float* w2 = (const float*)d_in[1];   // [2,2,3,4,128,128,16]
  const float* lo = (const float*)d_in[2];   // [2,2,4,128,128,16]
  float* out = (float*)d_out;                // [4,512,512,16]
  float* mid = (float*)d_ws;                 // [4 quadrants][4][256][256][16] = 64 MiB

  qshift_kernel<<<dim3(16, 16, 16), 256, 0, stream>>>(w2, lo, mid);
  farras_kernel<<<dim3(32, 32, 4), 256, 0, stream>>>(w1, mid, out);
}